// Round 9
// baseline (76.263 us; speedup 1.0000x reference)
//
#include <hip/hip_runtime.h>
#include <cmath>

#define B_  16
#define S_  512
#define DI  64
#define DS  64
#define RR  4
#define CH  8      // chunks
#define CL  64     // chunk length
#define CLIPM 1.0e6f

typedef float f32x4 __attribute__((ext_vector_type(4)));

// ws layout (floats):
#define WS_U    524288        // u    [B*S][DI]
#define WS_BM   1048576       // bm   [B*S][DS]
#define WS_CML  1572864       // cml  [B][DS]
#define WS_HIN  1573888       // h_in [B][CH][DI][DS]   (2 MB)
// total 2,098,176 floats ~= 8.4 MB (same as R3/R6 which ran -> ws_size ok)

// Chunk summaries: f32x4 per chain, [B][CH][DI][DS], at out+1024 (8 MB).
// kA writes, kB reads (kernel-boundary ordered), kC overwrites afterwards.

__device__ __forceinline__ float clampM(float v) {
    return fminf(fmaxf(v, -CLIPM), CLIPM);
}

// k1: 8 timesteps per block; Wx row `lane` held in VGPRs and reused 8x.
__global__ __launch_bounds__(64)
void ssm_k1(const float* __restrict__ x, const float* __restrict__ Wx,
            const float* __restrict__ bx, const float* __restrict__ Wdt,
            const float* __restrict__ bdt, const float* __restrict__ A_log,
            float* __restrict__ ws)
{
    __shared__ float xs[8][DI];
    __shared__ float dtr_s[8][RR];
    const int bt0  = blockIdx.x * 8;
    const int lane = threadIdx.x;

    #pragma unroll
    for (int r = 0; r < 8; ++r)
        xs[r][lane] = x[(size_t)(bt0 + r) * DI + lane];
    const float a_l = -expf(A_log[lane]);   // row 0 of A_log (rows identical)
    const float bxl = bx[lane];
    __syncthreads();

    // Wx row `lane` -> registers (one gather per block, reused 8x)
    f32x4 wxr[16];
    {
        const float* wr = Wx + lane * DI;
        #pragma unroll
        for (int i = 0; i < 16; ++i)
            wxr[i] = *reinterpret_cast<const f32x4*>(wr + 4 * i);
    }

    // Bm for 8 rows
    float accB[8];
    #pragma unroll
    for (int r = 0; r < 8; ++r) {
        float a = bxl;
        #pragma unroll
        for (int i = 0; i < 16; ++i) {
            const f32x4 xv4 = *reinterpret_cast<const f32x4*>(&xs[r][4 * i]);
            a += wxr[i].x * xv4.x + wxr[i].y * xv4.y + wxr[i].z * xv4.z + wxr[i].w * xv4.w;
        }
        accB[r] = a;
    }

    // dtr: lanes 0..31 -> (r = lane>>2, j = lane&3): row 64+j dot xs[r]
    if (lane < 32) {
        const int j = lane & 3, r = lane >> 2;
        float acc = bx[DS + j];
        const float* wdr = Wx + (DS + j) * DI;
        #pragma unroll
        for (int i = 0; i < 16; ++i) {
            const f32x4 w   = *reinterpret_cast<const f32x4*>(wdr + 4 * i);
            const f32x4 xv4 = *reinterpret_cast<const f32x4*>(&xs[r][4 * i]);
            acc += w.x * xv4.x + w.y * xv4.y + w.z * xv4.z + w.w * xv4.w;
        }
        dtr_s[r][j] = acc;
    }
    __syncthreads();

    // |a|^2 (row-independent)
    float qv = a_l * a_l;
    #pragma unroll
    for (int off = 32; off > 0; off >>= 1) qv += __shfl_xor(qv, off);

    const f32x4 wdt4 = *reinterpret_cast<const f32x4*>(Wdt + lane * RR);
    const float bdtl = bdt[lane];

    #pragma unroll
    for (int r = 0; r < 8; ++r) {
        float dtv = bdtl + dtr_s[r][0] * wdt4.x + dtr_s[r][1] * wdt4.y
                         + dtr_s[r][2] * wdt4.z + dtr_s[r][3] * wdt4.w;
        float sv = a_l * dtv;
        #pragma unroll
        for (int off = 32; off > 0; off >>= 1) sv += __shfl_xor(sv, off);

        const float E   = expm1f(sv);
        const float phi = (fabsf(sv) < 1e-3f)
                            ? fmaf(sv, fmaf(sv, 1.0f / 6.0f, 0.5f), 1.0f)
                            : (E / sv);
        const int bt = bt0 + r;
        ws[(size_t)bt * DI + lane]         = phi * dtv;
        ws[WS_U + (size_t)bt * DI + lane]  = xs[r][lane] * (E / qv) * a_l;
        ws[WS_BM + (size_t)bt * DI + lane] = accB[r];
    }

    if ((bt0 & (S_ - 1)) == S_ - 8) {   // block containing t = S-1
        float accC = bx[DS + RR + lane];
        const float* wc = Wx + (DS + RR + lane) * DI;
        #pragma unroll
        for (int i = 0; i < 16; ++i) {
            const f32x4 w   = *reinterpret_cast<const f32x4*>(wc + 4 * i);
            const f32x4 xv4 = *reinterpret_cast<const f32x4*>(&xs[7][4 * i]);
            accC += w.x * xv4.x + w.y * xv4.y + w.z * xv4.z + w.w * xv4.w;
        }
        ws[WS_CML + (bt0 >> 9) * DS + lane] = accC;
    }
}

// kA: EXACT chunk summary h -> clamp(alpha*h + beta, lo, hi)  (R6, unchanged)
__global__ __launch_bounds__(256)
void ssm_kA(const float* __restrict__ ws, const float* __restrict__ A_log,
            float* __restrict__ out)
{
    const int tid = threadIdx.x;
    const int c   = blockIdx.x & 7;
    const int dg  = (blockIdx.x >> 3) & 3;
    const int b   = blockIdx.x >> 5;
    const int dl  = tid >> 4;
    const int n0  = (tid & 15) << 2;
    const int d   = dg * 16 + dl;

    const f32x4 alog4 = *reinterpret_cast<const f32x4*>(A_log + n0);
    float an[4]  = { -expf(alog4.x), -expf(alog4.y), -expf(alog4.z), -expf(alog4.w) };
    float dlt[4];
    #pragma unroll
    for (int k = 0; k < 4; ++k) dlt[k] = (d == n0 + k) ? 1.0f : 0.0f;

    const float* phidt = ws + (size_t)(b * S_) * DI + d;
    const float* uws   = ws + WS_U  + (size_t)(b * S_) * DI + d;
    const float* bmp   = ws + WS_BM + (size_t)(b * S_) * DI + n0;

    float al[4], be[4], lo[4], hi[4];
    #pragma unroll
    for (int k = 0; k < 4; ++k) { al[k] = 1.0f; be[k] = 0.0f; lo[k] = -CLIPM; hi[k] = CLIPM; }

    const int t0 = c * CL;
    #pragma unroll 8
    for (int j = 0; j < CL; ++j) {
        const int t = t0 + j;
        const float pv = phidt[(size_t)t * DI];
        const float uv = uws[(size_t)t * DI];
        const f32x4 bv = *reinterpret_cast<const f32x4*>(bmp + (size_t)t * DI);
        const float bva[4] = { bv.x, bv.y, bv.z, bv.w };
        #pragma unroll
        for (int k = 0; k < 4; ++k) {
            const float av = fmaf(pv, an[k], dlt[k]);
            const float w  = uv * bva[k];
            al[k] = al[k] * av;
            be[k] = fmaf(av, be[k], w);
            const float u1 = fmaf(av, lo[k], w);
            const float u2 = fmaf(av, hi[k], w);
            lo[k] = clampM(fminf(u1, u2));
            hi[k] = clampM(fmaxf(u1, u2));
        }
    }

    f32x4* sum = reinterpret_cast<f32x4*>(out + 1024);
    const size_t sb = (((size_t)b * CH + c) * DI + d) * DS + n0;
    #pragma unroll
    for (int k = 0; k < 4; ++k) {
        f32x4 s = { al[k], be[k], lo[k], hi[k] };
        sum[sb + k] = s;
    }
}

// kB: sequential compose of the 8 chunk summaries; writes h_in. (R6, unchanged)
__global__ __launch_bounds__(256)
void ssm_kB(float* __restrict__ ws, const float* __restrict__ out)
{
    const int tid = threadIdx.x;
    const int dg  = blockIdx.x & 3;
    const int b   = blockIdx.x >> 2;
    const int dl  = tid >> 4;
    const int n0  = (tid & 15) << 2;
    const int d   = dg * 16 + dl;

    const f32x4* sum = reinterpret_cast<const f32x4*>(out + 1024);

    float h[4] = { 0.0f, 0.0f, 0.0f, 0.0f };
    #pragma unroll
    for (int c = 0; c < CH; ++c) {
        const size_t base = (((size_t)b * CH + c) * DI + d) * DS + n0;
        f32x4 hv = { h[0], h[1], h[2], h[3] };
        *reinterpret_cast<f32x4*>(ws + WS_HIN + base) = hv;
        #pragma unroll
        for (int k = 0; k < 4; ++k) {
            const f32x4 s = sum[base + k];
            h[k] = fminf(fmaxf(fmaf(s.x, h[k], s.y), s.z), s.w);
        }
    }
}

// kC: block = (b, chunk). 512 threads own all 64x64 chains (8 per thread);
// walks t linearly writing the FULL 16KB row per t -> each block's 1MB of
// output is written sequentially (HBM/L2-eviction friendly).
__global__ __launch_bounds__(512)
void ssm_kC(const float* __restrict__ ws, const float* __restrict__ x,
            const float* __restrict__ A_log, const float* __restrict__ Dp,
            float* __restrict__ out)
{
    __shared__ float pd_s[CL][DI];
    __shared__ float ud_s[CL][DI];
    __shared__ float bm_s[CL][DS];

    const int tid = threadIdx.x;
    const int n   = tid & 63;
    const int w   = tid >> 6;          // 0..7 -> d in {8w..8w+7}
    const int c   = blockIdx.x & 7;
    const int b   = blockIdx.x >> 3;
    const int t0  = c * CL;

    // stage the chunk's operand streams (coalesced, 8 floats/thread/array)
    {
        const int row = tid >> 3;
        const int col = (tid & 7) * 8;
        const size_t off = (size_t)row * DI + col;
        const float* pg = ws + (size_t)(b * S_ + t0) * DI;
        const float* ug = ws + WS_U  + (size_t)(b * S_ + t0) * DI;
        const float* bg = ws + WS_BM + (size_t)(b * S_ + t0) * DI;
        *reinterpret_cast<f32x4*>(&pd_s[row][col])     = *reinterpret_cast<const f32x4*>(pg + off);
        *reinterpret_cast<f32x4*>(&pd_s[row][col + 4]) = *reinterpret_cast<const f32x4*>(pg + off + 4);
        *reinterpret_cast<f32x4*>(&ud_s[row][col])     = *reinterpret_cast<const f32x4*>(ug + off);
        *reinterpret_cast<f32x4*>(&ud_s[row][col + 4]) = *reinterpret_cast<const f32x4*>(ug + off + 4);
        *reinterpret_cast<f32x4*>(&bm_s[row][col])     = *reinterpret_cast<const f32x4*>(bg + off);
        *reinterpret_cast<f32x4*>(&bm_s[row][col + 4]) = *reinterpret_cast<const f32x4*>(bg + off + 4);
    }

    const float a_n = -expf(A_log[n]);
    float h[8], dlt[8];
    {
        const float* hin = ws + WS_HIN + ((size_t)(b * CH + c) * DI) * DS;
        #pragma unroll
        for (int k = 0; k < 8; ++k) {
            h[k]   = hin[(size_t)(w * 8 + k) * DS + n];
            dlt[k] = (w * 8 + k == n) ? 1.0f : 0.0f;
        }
    }
    __syncthreads();

    float* pot = out + 1024 + (size_t)(b * S_ + t0) * (DI * DS) + (size_t)w * 8 * DS + n;
    #pragma unroll 8
    for (int j = 0; j < CL; ++j) {
        const f32x4 pv0 = *reinterpret_cast<const f32x4*>(&pd_s[j][w * 8]);
        const f32x4 pv1 = *reinterpret_cast<const f32x4*>(&pd_s[j][w * 8 + 4]);
        const f32x4 uv0 = *reinterpret_cast<const f32x4*>(&ud_s[j][w * 8]);
        const f32x4 uv1 = *reinterpret_cast<const f32x4*>(&ud_s[j][w * 8 + 4]);
        const float bv  = bm_s[j][n];
        const float pva[8] = { pv0.x, pv0.y, pv0.z, pv0.w, pv1.x, pv1.y, pv1.z, pv1.w };
        const float uva[8] = { uv0.x, uv0.y, uv0.z, uv0.w, uv1.x, uv1.y, uv1.z, uv1.w };
        float* poj = pot + (size_t)j * (DI * DS);
        #pragma unroll
        for (int k = 0; k < 8; ++k) {
            const float av = fmaf(pva[k], a_n, dlt[k]);
            h[k] = clampM(fmaf(av, h[k], uva[k] * bv));
            poj[k * DS] = h[k];
        }
    }

    if (c == CH - 1) {
        const float cmn = ws[WS_CML + b * DS + n];
        #pragma unroll
        for (int k = 0; k < 8; ++k) {
            float v = h[k] * cmn;
            #pragma unroll
            for (int off = 32; off > 0; off >>= 1) v += __shfl_xor(v, off);
            if (n == 0) {
                const int d = w * 8 + k;
                out[b * DI + d] = v + Dp[d] * x[((size_t)(b * S_) + S_ - 1) * DI + d];
            }
        }
    }
}

extern "C" void kernel_launch(void* const* d_in, const int* in_sizes, int n_in,
                              void* d_out, int out_size, void* d_ws, size_t ws_size,
                              hipStream_t stream)
{
    const float* x     = (const float*)d_in[0];
    const float* Wx    = (const float*)d_in[1];
    const float* bx    = (const float*)d_in[2];
    const float* Wdt   = (const float*)d_in[3];
    const float* bdt   = (const float*)d_in[4];
    const float* A_log = (const float*)d_in[5];
    const float* Dp    = (const float*)d_in[6];
    float* out = (float*)d_out;
    float* ws  = (float*)d_ws;

    ssm_k1<<<B_ * S_ / 8, 64, 0, stream>>>(x, Wx, bx, Wdt, bdt, A_log, ws);
    ssm_kA<<<B_ * 4 * CH, 256, 0, stream>>>(ws, A_log, out);
    ssm_kB<<<B_ * 4, 256, 0, stream>>>(ws, out);
    ssm_kC<<<B_ * CH, 512, 0, stream>>>(ws, x, A_log, Dp, out);
}